// Round 4
// baseline (590.580 us; speedup 1.0000x reference)
//
#include <hip/hip_runtime.h>
#include <hip/hip_bf16.h>

// B=16, N=1024, R=10, De=64, Dr=32, H=64, cat_in=960
// out[b,m,h] = relu( bias[h] + sum_r sum_n adj[b,r,m,n] * Yt[br,h,n] )
// Yt[br,h,n] = sum_d x[b,n,d]*W[h, r*96+d] + c[br,h]
// c[br,h]    = sum_d rel[br,d]*W[h, r*96+64+d]

typedef __bf16 bf16x8 __attribute__((ext_vector_type(8)));
typedef float  f32x4  __attribute__((ext_vector_type(4)));
typedef float  f32x8  __attribute__((ext_vector_type(8)));

// ---------------- prep kernel: c (fused) + Yt[br,h,n] (bf16, linear) ----------------
__global__ __launch_bounds__(256)
void rgcn_prep(const float* __restrict__ x, const float* __restrict__ rel,
               const float* __restrict__ W, __bf16* __restrict__ yt) {
    const int r = blockIdx.y, b = blockIdx.z;
    const int br = b * 10 + r;

    __shared__ float csh[64];
    if (threadIdx.x < 64) {
        const int h = threadIdx.x;
        const float* rp = rel + (size_t)br * 32;
        const float* wp = W + (size_t)h * 960 + r * 96 + 64;
        float a = 0.f;
#pragma unroll
        for (int d = 0; d < 32; ++d) a += rp[d] * wp[d];
        csh[h] = a;
    }
    __syncthreads();

    const int n = blockIdx.x * 256 + threadIdx.x;   // 0..1023
    float xr[64];
    const float* xp = x + ((size_t)b * 1024 + n) * 64;
#pragma unroll
    for (int j = 0; j < 16; ++j) {
        const float4 v = *(const float4*)(xp + j * 4);
        xr[j * 4 + 0] = v.x; xr[j * 4 + 1] = v.y;
        xr[j * 4 + 2] = v.z; xr[j * 4 + 3] = v.w;
    }

    const float* wbase = W + r * 96;                 // W[h*960 + r*96 + d]
    __bf16* yb = yt + ((size_t)br << 16) + n;        // Yt[br][h][n], linear
    for (int h = 0; h < 64; ++h) {                   // h,d wave-uniform -> W scalar loads
        float acc = csh[h];
        const float* wr = wbase + (size_t)h * 960;
#pragma unroll
        for (int d = 0; d < 64; ++d) acc += xr[d] * wr[d];
        yb[(size_t)h << 10] = (__bf16)acc;
    }
}

// ---------------- main kernel ----------------
// grid (16*RSPAN, 8 mtile), 512 thr = 8 waves; wave owns 16 m x 64 h.
// LDS 64 KiB: half-K Yt slice [64][512] bf16, swizzled (n ^ ((h&7)<<3)) -> 2-way (free).
// 2 blocks/CU, 4 waves/SIMD: staging bubbles of one block overlap the other's stream.
// adj is the only HBM stream: 4-deep f32x8 prefetch on a global step counter that
// crosses half/relation boundaries (no wrap waste; clamped tail).
// A-frag: adj row (w*16+lm), k=(lane>>4)*8+j ; B-frag same k-map (k-perm cancels).
// C/D: col=lane&15 (h), row=(lane>>4)*4+reg (m) — validated rounds 1-3.
template<int NRI, bool FUSE>
__global__ __launch_bounds__(512, 4)
void rgcn_main(const float* __restrict__ adj, const __bf16* __restrict__ yt,
               float* __restrict__ partial, const float* __restrict__ bias,
               float* __restrict__ dst) {
    constexpr int RSPAN = 10 / NRI;
    const int bx = blockIdx.x;
    const int b  = bx / RSPAN, r0 = bx % RSPAN;
    const int mtile = blockIdx.y;                   // 0..7
    const int tid = threadIdx.x;
    const int w = tid >> 6, lane = tid & 63;
    const int g = lane >> 4, lm = lane & 15;
    const int mloc = mtile * 128 + w * 16 + lm;     // adj row this lane streams
    const int msk = (lm & 7) << 3;

    __shared__ __bf16 sh[32768];                    // 64 KiB: [64][512] half-slice

    const int brbase = b * 10 + r0;
    constexpr int SMAX = NRI * 32 - 1;

    // adj address for global step s (clamped): relation brbase + (s/32)*RSPAN, col (s%32)*32
    auto aaddr = [&](int s) -> const float* {
        const int sc = s < SMAX ? s : SMAX;
        const int r  = (sc >> 5) * RSPAN;
        const int c  = (sc & 31) << 5;
        return adj + (((size_t)((brbase + r) * 1024 + mloc)) << 10) + c + g * 8;
    };

    f32x4 acc[4] = {};
    f32x8 pf[4];
#pragma unroll
    for (int p = 0; p < 4; ++p)
        pf[p] = __builtin_nontemporal_load((const f32x8*)aaddr(p));

    for (int i = 0; i < NRI; ++i) {
        const __bf16* ysrc = yt + ((size_t)(brbase + i * RSPAN) << 16);
#pragma unroll
        for (int kh = 0; kh < 2; ++kh) {
            // ---- stage half kh: [64][512] from ysrc (+kh*512), reg-batched ----
            if (i || kh) __syncthreads();           // previous half fully consumed
#pragma unroll
            for (int it2 = 0; it2 < 2; ++it2) {
                uint4 st[4];
#pragma unroll
                for (int j = 0; j < 4; ++j) {
                    const int e = ((it2 * 4 + j) * 512 + tid) * 8;   // elem in half
                    const int h = e >> 9, nn = e & 511;
                    st[j] = *(const uint4*)(ysrc + (h << 10) + kh * 512 + nn);
                }
#pragma unroll
                for (int j = 0; j < 4; ++j) {
                    const int e = ((it2 * 4 + j) * 512 + tid) * 8;
                    const int h = e >> 9, nn = e & 511;
                    *(uint4*)(sh + (h << 9) + (nn ^ ((h & 7) << 3))) = st[j];
                }
            }
            __syncthreads();

            // ---- 16 MFMA steps over this half; prefetch runs 4 ahead globally ----
#pragma unroll 4
            for (int s16 = 0; s16 < 16; ++s16) {
                const int s = i * 32 + kh * 16 + s16;
                const int slot = s16 & 3;           // s%4 == s16%4
                const f32x8 cur = pf[slot];
                pf[slot] = __builtin_nontemporal_load((const f32x8*)aaddr(s + 4));
                bf16x8 av;
#pragma unroll
                for (int j = 0; j < 8; ++j) av[j] = (__bf16)cur[j];
                const int nc = (s16 << 5) + g * 8;
#pragma unroll
                for (int hf = 0; hf < 4; ++hf) {
                    const int h = hf * 16 + lm;
                    const bf16x8 bv = *(const bf16x8*)(sh + (h << 9) + (nc ^ msk));
                    acc[hf] = __builtin_amdgcn_mfma_f32_16x16x32_bf16(av, bv, acc[hf], 0, 0, 0);
                }
            }
        }
    }

    // ---- epilogue ----
    if (FUSE) {
        float* db = dst + (((size_t)b << 10) + mtile * 128 + w * 16) * 64;
#pragma unroll
        for (int hf = 0; hf < 4; ++hf) {
            const float bb = bias[hf * 16 + lm];
#pragma unroll
            for (int reg = 0; reg < 4; ++reg) {
                const int ml = g * 4 + reg;
                db[(size_t)ml * 64 + hf * 16 + lm] = fmaxf(acc[hf][reg] + bb, 0.f);
            }
        }
    } else {
        float* pb = partial + (((size_t)(r0 * 16 + b)) << 16)
                  + (size_t)(mtile * 128 + w * 16) * 64;
#pragma unroll
        for (int hf = 0; hf < 4; ++hf)
#pragma unroll
            for (int reg = 0; reg < 4; ++reg) {
                const int ml = g * 4 + reg;
                pb[(size_t)ml * 64 + hf * 16 + lm] = acc[hf][reg];
            }
    }
}

// ---------------- epilogue: sum NP partial slices + bias + relu ----------------
template<int NP>
__global__ __launch_bounds__(256)
void rgcn_epi(const float* __restrict__ partial, const float* __restrict__ bias,
              float* __restrict__ dst) {
    const size_t i = (size_t)blockIdx.x * 256 + threadIdx.x;  // f32x4 index, 262144 total
    const size_t off = i * 4;                                  // float idx into [16][1024][64]
    const size_t b = off >> 16;
    const size_t inner = off & 65535;
    f32x4 s = {};
#pragma unroll
    for (int p = 0; p < NP; ++p)
        s += *(const f32x4*)(partial + (((size_t)(p * 16) + b) << 16) + inner);
    const f32x4 bv = *(const f32x4*)(bias + (int)(off & 63));
#pragma unroll
    for (int j = 0; j < 4; ++j) s[j] = fmaxf(s[j] + bv[j], 0.f);
    *(f32x4*)(dst + off) = s;
}

extern "C" void kernel_launch(void* const* d_in, const int* in_sizes, int n_in,
                              void* d_out, int out_size, void* d_ws, size_t ws_size,
                              hipStream_t stream) {
    const float* x   = (const float*)d_in[0];   // [16,1024,64]
    const float* rel = (const float*)d_in[1];   // [16,10,32]
    const float* adj = (const float*)d_in[2];   // [16,10,1024,1024]
    const float* W0  = (const float*)d_in[3];   // [64,960]
    const float* b0  = (const float*)d_in[4];   // [64]
    const float* W1  = (const float*)d_in[5];
    const float* b1  = (const float*)d_in[6];
    float* out = (float*)d_out;                 // [16,1024,64]

    char* ws = (char*)d_ws;
    __bf16* Yt  = (__bf16*)ws;                  // 20,971,520 B (160 x 64 x 1024 bf16)
    float* x2   = (float*)(ws + 20971520);      //  4,194,304 B
    float* part = (float*)(ws + 25165824);      // up to 41,943,040 B
    const size_t need1 = 25165824u + 41943040u; // 10 f32 slices
    const size_t need2 = 25165824u + 20971520u; //  5 f32 slices

    for (int layer = 0; layer < 2; ++layer) {
        const float* xin  = layer ? x2 : x;
        const float* W    = layer ? W1 : W0;
        const float* bias = layer ? b1 : b0;
        float* dst        = layer ? out : x2;

        rgcn_prep<<<dim3(4, 10, 16), 256, 0, stream>>>(xin, rel, W, Yt);
        if (ws_size >= need1) {
            rgcn_main<1, false><<<dim3(160, 8), 512, 0, stream>>>(adj, Yt, part, nullptr, nullptr);
            rgcn_epi<10><<<1024, 256, 0, stream>>>(part, bias, dst);
        } else if (ws_size >= need2) {
            rgcn_main<2, false><<<dim3(80, 8), 512, 0, stream>>>(adj, Yt, part, nullptr, nullptr);
            rgcn_epi<5><<<1024, 256, 0, stream>>>(part, bias, dst);
        } else {
            rgcn_main<10, true><<<dim3(16, 8), 512, 0, stream>>>(adj, Yt, nullptr, bias, dst);
        }
    }
}